// Round 5
// baseline (223.015 us; speedup 1.0000x reference)
//
#include <hip/hip_runtime.h>

// VarianceLoss via one-hot MFMA segment reduction.  B=8, C=4, H=W=1024, NSEG=65.
//
// C[64 segs][cols] += Onehot[seg][px] * Payload[px][cols], K = pixels.
//  - A (one-hot, exact 0/1 in bf16) built in registers from staged seg ids
//    with packed u16 ops.  B = staged payload, bf16 hi+lo split: cols 0..4 =
//    {p0,p1,p2,qq,1(cnt)} hi, cols 8..12 = lo parts.  hi+lo merged in the
//    epilogue => full ~f32 precision from bf16 MFMAs (R3: absmax 0.0).
//  - A and B fragments are addressed through the SAME assumed (lane>>4,j)->k
//    map, so a wrong assumption cancels (A/B k-layouts are symmetric).
//  - R4: 1-deep software pipeline (prefetch next round's global loads into
//    regs before processing current) + gridx 256 (24 waves/CU, was 16) to
//    attack the latency-bound gap (measured ~70us vs ~18us VALU floor).

typedef unsigned short u16x2 __attribute__((ext_vector_type(2)));
typedef unsigned int   u32x4 __attribute__((ext_vector_type(4)));
typedef short          s16x8 __attribute__((ext_vector_type(8)));   // 8 x bf16
typedef float          f32x4 __attribute__((ext_vector_type(4)));

constexpr int   B_    = 8;
constexpr int   SEGS  = 64;      // segments 1..64 (segment 0 masked out by ref)
constexpr int   VALS  = 5;       // p0,p1,p2,qq,cnt
constexpr float EPS_  = 1e-8f;

constexpr int PLANE   = 528;               // bytes per plane (512 + bank skew)
constexpr int NSLOT   = 11;                // 4 hi, 4 lo, ONES, ZERO, seg
constexpr int WLDS    = NSLOT * PLANE;     // 5808 B per wave
constexpr int LDS_SZ  = (4 * WLDS > 16384) ? 4 * WLDS : 16384;

__device__ __forceinline__ unsigned asu(float f)  { return __float_as_uint(f); }
__device__ __forceinline__ float    asf(unsigned u){ return __uint_as_float(u); }

__global__ __launch_bounds__(256) void vl_accum(const float* __restrict__ logit,
                                                const int*   __restrict__ inst,
                                                float* __restrict__ acc,
                                                int N, int ppb)
{
    __shared__ __align__(16) unsigned char lds[LDS_SZ];

    const int tid  = threadIdx.x;
    const int wid  = tid >> 6;
    const int lane = tid & 63;
    const int col  = lane & 15;
    const int quad = lane >> 4;
    const int wbase = wid * WLDS;

    // init ONES (slot 8) and ZERO (slot 9) planes, 512B each used
    *(uint2*)(lds + wbase + 8 * PLANE + lane * 8) = make_uint2(0x3F803F80u, 0x3F803F80u);
    *(uint2*)(lds + wbase + 9 * PLANE + lane * 8) = make_uint2(0u, 0u);

    // B-read plane per column
    int pl;
    if      (col < 4)              pl = col;        // hi payload
    else if (col >= 8 && col < 12) pl = col - 4;    // lo payload
    else if (col == 4)             pl = 8;          // cnt hi = 1.0
    else                           pl = 9;          // zero
    const int bRd   = wbase + pl * PLANE + quad * 16;   // + kt*64
    const int segRd = wbase + 10 * PLANE + quad * 16;   // + kt*64
    const int segWr = wbase + 10 * PLANE + lane * 8;

    u16x2 rowdup[4];
#pragma unroll
    for (int t = 0; t < 4; ++t) {
        unsigned short rw = (unsigned short)(t * 16 + col);
        rowdup[t] = (u16x2){rw, rw};
    }
    const u16x2 one2  = (u16x2){1, 1};
    const u16x2 bf1p  = (u16x2){0x3F80, 0x3F80};

    const int b = blockIdx.y;
    const float* __restrict__ l0 = logit + (size_t)b * 4 * N;
    const int*   __restrict__ ib = inst  + (size_t)b * N;

    f32x4 acc0 = {0.f,0.f,0.f,0.f}, acc1 = {0.f,0.f,0.f,0.f};
    f32x4 acc2 = {0.f,0.f,0.f,0.f}, acc3 = {0.f,0.f,0.f,0.f};

    const int blockStart = blockIdx.x * ppb;
    const int rounds = ppb >> 10;
    const int base0  = blockStart + (wid << 8) + (lane << 2);

#define LOAD_ROUND(R, X0, X1, X2, X3, SG)                                       \
    {                                                                           \
        const int q  = base0 + ((R) << 10);                                     \
        const bool ok = (q + 4 <= N);                                           \
        const int qc = ok ? q : 0;                                              \
        X0 = *(const float4*)(l0 + qc);                                         \
        X1 = *(const float4*)(l0 + (size_t)N     + qc);                         \
        X2 = *(const float4*)(l0 + (size_t)2 * N + qc);                         \
        X3 = *(const float4*)(l0 + (size_t)3 * N + qc);                         \
        int4 sgt = *(const int4*)(ib + qc);                                     \
        SG = ok ? sgt : make_int4(0, 0, 0, 0);                                  \
    }

    float4 cx0, cx1, cx2, cx3; int4 csg;      // current round (pre-loaded)
    if (rounds > 0) LOAD_ROUND(0, cx0, cx1, cx2, cx3, csg)

    for (int r = 0; r < rounds; ++r) {
        float4 nx0, nx1, nx2, nx3; int4 nsg;  // prefetch next round
        if (r + 1 < rounds) LOAD_ROUND(r + 1, nx0, nx1, nx2, nx3, nsg)

        const float c0[4] = {cx0.x, cx0.y, cx0.z, cx0.w};
        const float c1[4] = {cx1.x, cx1.y, cx1.z, cx1.w};
        const float c2[4] = {cx2.x, cx2.y, cx2.z, cx2.w};
        const float c3[4] = {cx3.x, cx3.y, cx3.z, cx3.w};

        float P0[4], P1[4], P2[4], QQ[4];
#pragma unroll
        for (int i = 0; i < 4; ++i) {
            float va = c0[i], vb = c1[i], vc = c2[i], vd = c3[i];
            float m  = fmaxf(fmaxf(va, vb), fmaxf(vc, vd));
            float e0 = __expf(va - m);
            float e1 = __expf(vb - m);
            float e2 = __expf(vc - m);
            float e3 = __expf(vd - m);
            float rr = 1.0f / (e0 + e1 + e2 + e3);
            float q0 = e0 * rr, q1 = e1 * rr, q2 = e2 * rr, q3 = e3 * rr;
            P0[i] = q0; P1[i] = q1; P2[i] = q2;
            QQ[i] = q0*q0 + q1*q1 + q2*q2 + q3*q3;
        }

        // stage one plane: hi (truncated bf16) to slot p, lo residual to p+4
#define STAGE_PLANE(P, ARR)                                                     \
        {                                                                       \
            unsigned a0 = asu(ARR[0]), a1 = asu(ARR[1]);                        \
            unsigned a2 = asu(ARR[2]), a3 = asu(ARR[3]);                        \
            unsigned h1m = a1 & 0xFFFF0000u, h3m = a3 & 0xFFFF0000u;            \
            unsigned hi01 = (a0 >> 16) | h1m;                                   \
            unsigned hi23 = (a2 >> 16) | h3m;                                   \
            float l0f = ARR[0] - asf(a0 & 0xFFFF0000u);                         \
            float l1f = ARR[1] - asf(h1m);                                      \
            float l2f = ARR[2] - asf(a2 & 0xFFFF0000u);                         \
            float l3f = ARR[3] - asf(h3m);                                      \
            unsigned lo01 = (asu(l0f) >> 16) | (asu(l1f) & 0xFFFF0000u);        \
            unsigned lo23 = (asu(l2f) >> 16) | (asu(l3f) & 0xFFFF0000u);        \
            *(uint2*)(lds + wbase + (P) * PLANE + lane * 8)     = make_uint2(hi01, hi23); \
            *(uint2*)(lds + wbase + ((P)+4) * PLANE + lane * 8) = make_uint2(lo01, lo23); \
        }
        STAGE_PLANE(0, P0)
        STAGE_PLANE(1, P1)
        STAGE_PLANE(2, P2)
        STAGE_PLANE(3, QQ)
#undef STAGE_PLANE

        // seg-1 as u16 (seg 0 / invalid -> 0xFFFF, matches no row)
        {
            unsigned r0 = (unsigned)(csg.x - 1) & 0xFFFFu;
            unsigned r1 = (unsigned)(csg.y - 1) & 0xFFFFu;
            unsigned r2 = (unsigned)(csg.z - 1) & 0xFFFFu;
            unsigned r3 = (unsigned)(csg.w - 1) & 0xFFFFu;
            *(uint2*)(lds + segWr) = make_uint2(r0 | (r1 << 16), r2 | (r3 << 16));
        }
        // own-wave RAW through LDS: compiler inserts lgkmcnt waits.

#pragma unroll
        for (int kt = 0; kt < 8; ++kt) {
            s16x8 bfrag = *(const s16x8*)(lds + bRd   + kt * 64);
            u32x4 sv    = *(const u32x4*)(lds + segRd + kt * 64);

#define DO_TILE(T, ACC)                                                         \
            {                                                                   \
                u32x4 fr;                                                       \
                _Pragma("unroll")                                               \
                for (int i = 0; i < 4; ++i) {                                   \
                    u16x2 sp  = __builtin_bit_cast(u16x2, sv[i]);               \
                    u16x2 d   = sp - rowdup[T];                                 \
                    u16x2 mn  = __builtin_elementwise_min(d, one2);             \
                    u16x2 inv = one2 - mn;                                      \
                    u16x2 f   = inv * bf1p;                                     \
                    fr[i] = __builtin_bit_cast(unsigned, f);                    \
                }                                                               \
                s16x8 afrag = __builtin_bit_cast(s16x8, fr);                    \
                ACC = __builtin_amdgcn_mfma_f32_16x16x32_bf16(afrag, bfrag, ACC, 0, 0, 0); \
            }
            DO_TILE(0, acc0)
            DO_TILE(1, acc1)
            DO_TILE(2, acc2)
            DO_TILE(3, acc3)
#undef DO_TILE
        }

        cx0 = nx0; cx1 = nx1; cx2 = nx2; cx3 = nx3; csg = nsg;
    }
#undef LOAD_ROUND

    // ---- cross-wave reduce + global atomics ----
    __syncthreads();                       // all waves done reading their planes
    float* cl = (float*)lds;               // [w][t][lane][reg] f32
    {
        const int base = ((wid * 4) * 64 + lane) * 4;
        *(f32x4*)(cl + base)            = acc0;
        *(f32x4*)(cl + base + 64 * 4)   = acc1;
        *(f32x4*)(cl + base + 128 * 4)  = acc2;
        *(f32x4*)(cl + base + 192 * 4)  = acc3;
    }
    __syncthreads();

    for (int i = tid; i < SEGS * VALS; i += 256) {
        const int row = i / VALS;          // 0..63  (= seg-1)
        const int cc  = i - row * VALS;    // 0..4
        const int t   = row >> 4;
        const int rr  = row & 15;
        const int g   = rr >> 2;
        const int reg = rr & 3;
        const int lhi = g * 16 + cc;
        const int llo = lhi + 8;
        float v = 0.0f;
#pragma unroll
        for (int w = 0; w < 4; ++w) {
            v += cl[((w * 4 + t) * 64 + lhi) * 4 + reg];
            v += cl[((w * 4 + t) * 64 + llo) * 4 + reg];
        }
        unsafeAtomicAdd(acc + ((size_t)blockIdx.y * SEGS + row) * VALS + cc, v);
    }
}

__global__ __launch_bounds__(256) void vl_finalize(const float* __restrict__ acc,
                                                   float* __restrict__ out)
{
    __shared__ float sum_var[B_];
    __shared__ float num_ids[B_];
    if (threadIdx.x < B_) { sum_var[threadIdx.x] = 0.0f; num_ids[threadIdx.x] = 0.0f; }
    __syncthreads();

    for (int i = threadIdx.x; i < B_ * SEGS; i += 256) {
        const float* a = acc + (size_t)i * VALS;
        const int b = i >> 6;
        const float cnt = a[4];
        if (cnt > 1.0f) {
            const float inv_n = 1.0f / cnt;       // n_safe = cnt (cnt > 0)
            const float denom = cnt - 1.0f;       // cnt > 1
            const float s0 = a[0], s1 = a[1], s2 = a[2];
            const float s3 = cnt - s0 - s1 - s2;  // p's sum to 1 per pixel
            const float ssum2 = s0*s0 + s1*s1 + s2*s2 + s3*s3;
            const float sv = (a[3] - ssum2 * inv_n) / denom;
            atomicAdd(&sum_var[b], sv);
        }
        if (cnt > 0.0f) atomicAdd(&num_ids[b], 1.0f);
    }
    __syncthreads();

    if (threadIdx.x == 0) {
        float loss = 0.0f;
#pragma unroll
        for (int b = 0; b < B_; ++b) loss += sum_var[b] / (num_ids[b] + EPS_);
        out[0] = loss / (float)B_;
    }
}

extern "C" void kernel_launch(void* const* d_in, const int* in_sizes, int n_in,
                              void* d_out, int out_size, void* d_ws, size_t ws_size,
                              hipStream_t stream) {
    const float* logit = (const float*)d_in[0];
    const int*   inst  = (const int*)d_in[1];
    float* out = (float*)d_out;
    float* acc = (float*)d_ws;                      // B_*SEGS*VALS f32 = 10240 B

    const int totalPix = in_sizes[1];               // B*H*W
    const int N = totalPix / B_;                    // H*W per batch

    hipMemsetAsync(acc, 0, (size_t)B_ * SEGS * VALS * sizeof(float), stream);

    const int gridx = 256;                          // 2048 blocks -> 24 waves/CU
    int ppb = (N + gridx - 1) / gridx;
    ppb = (ppb + 1023) & ~1023;                     // 1024-px block rounds

    dim3 grid(gridx, B_);
    vl_accum<<<grid, 256, 0, stream>>>(logit, inst, acc, N, ppb);
    vl_finalize<<<1, 256, 0, stream>>>(acc, out);
}

// Round 6
// 221.579 us; speedup vs baseline: 1.0065x; 1.0065x over previous
//
#include <hip/hip_runtime.h>

// VarianceLoss via one-hot MFMA segment reduction.  B=8, C=4, H=W=1024, NSEG=65.
//
// C[64 segs][cols] += Onehot[seg][px] * Payload[px][cols], K = pixels.
//  - A (one-hot, exact 0/1 in bf16) built in registers from staged seg ids
//    with packed u16 ops.  B = staged payload, bf16 hi+lo split: cols 0..3 =
//    {p0,p1,p2,qq} hi, cols 8..11 = lo parts, col 4 = cnt (const 1.0),
//    others 0.  hi+lo merged in the epilogue => ~f32 precision (absmax 0.0).
//  - R5: constant B-columns (cnt=1.0 / zeros) come from v_cndmask after the
//    ds_read instead of dedicated ONES/ZERO LDS planes: 11 -> 9 planes,
//    LDS 23.2 KB -> 19.0 KB => 8 blocks/CU resident (was 6, with a 2-block
//    second-generation tail that matched the measured 37.8% occupancy).

typedef unsigned short u16x2 __attribute__((ext_vector_type(2)));
typedef unsigned int   u32x4 __attribute__((ext_vector_type(4)));
typedef short          s16x8 __attribute__((ext_vector_type(8)));   // 8 x bf16
typedef float          f32x4 __attribute__((ext_vector_type(4)));

constexpr int   B_    = 8;
constexpr int   SEGS  = 64;      // segments 1..64 (segment 0 masked out by ref)
constexpr int   VALS  = 5;       // p0,p1,p2,qq,cnt
constexpr float EPS_  = 1e-8f;

constexpr int PLANE   = 528;               // bytes per plane (512 + bank skew)
constexpr int NSLOT   = 9;                 // hi0,lo0,hi1,lo1,hi2,lo2,hi3,lo3,seg
constexpr int WLDS    = NSLOT * PLANE;     // 4752 B per wave
constexpr int LDS_SZ  = (4 * WLDS > 16384) ? 4 * WLDS : 16384;   // 19008

__device__ __forceinline__ unsigned asu(float f)  { return __float_as_uint(f); }
__device__ __forceinline__ float    asf(unsigned u){ return __uint_as_float(u); }

__global__ __launch_bounds__(256) void vl_accum(const float* __restrict__ logit,
                                                const int*   __restrict__ inst,
                                                float* __restrict__ acc,
                                                int N, int ppb)
{
    __shared__ __align__(16) unsigned char lds[LDS_SZ];

    const int tid  = threadIdx.x;
    const int wid  = tid >> 6;
    const int lane = tid & 63;
    const int col  = lane & 15;
    const int quad = lane >> 4;
    const int wbase = wid * WLDS;

    // B-read plane per column: slot 2c = hi_c, 2c+1 = lo_c (c = 0..3), 8 = seg
    const bool selLds = (col < 4) | (col >= 8 && col < 12);
    const unsigned cword = (col == 4) ? 0x3F803F80u : 0u;   // cnt hi = 1.0
    const int pl = (col < 4) ? (2 * col)
                 : ((col >= 8 && col < 12) ? (2 * (col - 8) + 1) : 0);
    const int bRd   = wbase + pl * PLANE + quad * 16;   // + kt*64
    const int segRd = wbase + 8 * PLANE + quad * 16;    // + kt*64
    const int segWr = wbase + 8 * PLANE + lane * 8;

    u16x2 rowdup[4];
#pragma unroll
    for (int t = 0; t < 4; ++t) {
        unsigned short rw = (unsigned short)(t * 16 + col);
        rowdup[t] = (u16x2){rw, rw};
    }
    const u16x2 one2  = (u16x2){1, 1};
    const u16x2 bf1p  = (u16x2){0x3F80, 0x3F80};

    const int b = blockIdx.y;
    const float* __restrict__ l0 = logit + (size_t)b * 4 * N;
    const int*   __restrict__ ib = inst  + (size_t)b * N;

    f32x4 acc0 = {0.f,0.f,0.f,0.f}, acc1 = {0.f,0.f,0.f,0.f};
    f32x4 acc2 = {0.f,0.f,0.f,0.f}, acc3 = {0.f,0.f,0.f,0.f};

    const int blockStart = blockIdx.x * ppb;
    const int rounds = ppb >> 10;
    const int base0  = blockStart + (wid << 8) + (lane << 2);

#define LOAD_ROUND(R, X0, X1, X2, X3, SG)                                       \
    {                                                                           \
        const int q  = base0 + ((R) << 10);                                     \
        const bool ok = (q + 4 <= N);                                           \
        const int qc = ok ? q : 0;                                              \
        X0 = *(const float4*)(l0 + qc);                                         \
        X1 = *(const float4*)(l0 + (size_t)N     + qc);                         \
        X2 = *(const float4*)(l0 + (size_t)2 * N + qc);                         \
        X3 = *(const float4*)(l0 + (size_t)3 * N + qc);                         \
        int4 sgt = *(const int4*)(ib + qc);                                     \
        SG = ok ? sgt : make_int4(0, 0, 0, 0);                                  \
    }

    float4 cx0, cx1, cx2, cx3; int4 csg;      // current round (pre-loaded)
    if (rounds > 0) LOAD_ROUND(0, cx0, cx1, cx2, cx3, csg)

    for (int r = 0; r < rounds; ++r) {
        float4 nx0, nx1, nx2, nx3; int4 nsg;  // prefetch next round
        if (r + 1 < rounds) LOAD_ROUND(r + 1, nx0, nx1, nx2, nx3, nsg)

        const float c0[4] = {cx0.x, cx0.y, cx0.z, cx0.w};
        const float c1[4] = {cx1.x, cx1.y, cx1.z, cx1.w};
        const float c2[4] = {cx2.x, cx2.y, cx2.z, cx2.w};
        const float c3[4] = {cx3.x, cx3.y, cx3.z, cx3.w};

        float P0[4], P1[4], P2[4], QQ[4];
#pragma unroll
        for (int i = 0; i < 4; ++i) {
            float va = c0[i], vb = c1[i], vc = c2[i], vd = c3[i];
            float m  = fmaxf(fmaxf(va, vb), fmaxf(vc, vd));
            float e0 = __expf(va - m);
            float e1 = __expf(vb - m);
            float e2 = __expf(vc - m);
            float e3 = __expf(vd - m);
            float rr = 1.0f / (e0 + e1 + e2 + e3);
            float q0 = e0 * rr, q1 = e1 * rr, q2 = e2 * rr, q3 = e3 * rr;
            P0[i] = q0; P1[i] = q1; P2[i] = q2;
            QQ[i] = q0*q0 + q1*q1 + q2*q2 + q3*q3;
        }

        // stage one value: hi (truncated bf16) to slot 2P, lo residual to 2P+1
#define STAGE_PLANE(P, ARR)                                                     \
        {                                                                       \
            unsigned a0 = asu(ARR[0]), a1 = asu(ARR[1]);                        \
            unsigned a2 = asu(ARR[2]), a3 = asu(ARR[3]);                        \
            unsigned h1m = a1 & 0xFFFF0000u, h3m = a3 & 0xFFFF0000u;            \
            unsigned hi01 = (a0 >> 16) | h1m;                                   \
            unsigned hi23 = (a2 >> 16) | h3m;                                   \
            float l0f = ARR[0] - asf(a0 & 0xFFFF0000u);                         \
            float l1f = ARR[1] - asf(h1m);                                      \
            float l2f = ARR[2] - asf(a2 & 0xFFFF0000u);                         \
            float l3f = ARR[3] - asf(h3m);                                      \
            unsigned lo01 = (asu(l0f) >> 16) | (asu(l1f) & 0xFFFF0000u);        \
            unsigned lo23 = (asu(l2f) >> 16) | (asu(l3f) & 0xFFFF0000u);        \
            *(uint2*)(lds + wbase + (2*(P)) * PLANE + lane * 8)   = make_uint2(hi01, hi23); \
            *(uint2*)(lds + wbase + (2*(P)+1) * PLANE + lane * 8) = make_uint2(lo01, lo23); \
        }
        STAGE_PLANE(0, P0)
        STAGE_PLANE(1, P1)
        STAGE_PLANE(2, P2)
        STAGE_PLANE(3, QQ)
#undef STAGE_PLANE

        // seg-1 as u16 (seg 0 / invalid -> 0xFFFF, matches no row)
        {
            unsigned r0 = (unsigned)(csg.x - 1) & 0xFFFFu;
            unsigned r1 = (unsigned)(csg.y - 1) & 0xFFFFu;
            unsigned r2 = (unsigned)(csg.z - 1) & 0xFFFFu;
            unsigned r3 = (unsigned)(csg.w - 1) & 0xFFFFu;
            *(uint2*)(lds + segWr) = make_uint2(r0 | (r1 << 16), r2 | (r3 << 16));
        }
        // own-wave RAW through LDS: compiler inserts lgkmcnt waits.

#pragma unroll
        for (int kt = 0; kt < 8; ++kt) {
            s16x8 braw = *(const s16x8*)(lds + bRd   + kt * 64);
            u32x4 sv   = *(const u32x4*)(lds + segRd + kt * 64);
            u32x4 bw   = __builtin_bit_cast(u32x4, braw);
#pragma unroll
            for (int i = 0; i < 4; ++i) bw[i] = selLds ? bw[i] : cword;
            s16x8 bfrag = __builtin_bit_cast(s16x8, bw);

#define DO_TILE(T, ACC)                                                         \
            {                                                                   \
                u32x4 fr;                                                       \
                _Pragma("unroll")                                               \
                for (int i = 0; i < 4; ++i) {                                   \
                    u16x2 sp  = __builtin_bit_cast(u16x2, sv[i]);               \
                    u16x2 d   = sp - rowdup[T];                                 \
                    u16x2 mn  = __builtin_elementwise_min(d, one2);             \
                    u16x2 inv = one2 - mn;                                      \
                    u16x2 f   = inv * bf1p;                                     \
                    fr[i] = __builtin_bit_cast(unsigned, f);                    \
                }                                                               \
                s16x8 afrag = __builtin_bit_cast(s16x8, fr);                    \
                ACC = __builtin_amdgcn_mfma_f32_16x16x32_bf16(afrag, bfrag, ACC, 0, 0, 0); \
            }
            DO_TILE(0, acc0)
            DO_TILE(1, acc1)
            DO_TILE(2, acc2)
            DO_TILE(3, acc3)
#undef DO_TILE
        }

        cx0 = nx0; cx1 = nx1; cx2 = nx2; cx3 = nx3; csg = nsg;
    }
#undef LOAD_ROUND

    // ---- cross-wave reduce + global atomics (aliases staging LDS) ----
    __syncthreads();                       // all waves done reading their planes
    float* cl = (float*)lds;               // [w][t][lane][reg] f32 = 16 KB
    {
        const int base = ((wid * 4) * 64 + lane) * 4;
        *(f32x4*)(cl + base)            = acc0;
        *(f32x4*)(cl + base + 64 * 4)   = acc1;
        *(f32x4*)(cl + base + 128 * 4)  = acc2;
        *(f32x4*)(cl + base + 192 * 4)  = acc3;
    }
    __syncthreads();

    for (int i = tid; i < SEGS * VALS; i += 256) {
        const int row = i / VALS;          // 0..63  (= seg-1)
        const int cc  = i - row * VALS;    // 0..4
        const int t   = row >> 4;
        const int rr  = row & 15;
        const int g   = rr >> 2;
        const int reg = rr & 3;
        const int lhi = g * 16 + cc;
        const int llo = lhi + 8;
        float v = 0.0f;
#pragma unroll
        for (int w = 0; w < 4; ++w) {
            v += cl[((w * 4 + t) * 64 + lhi) * 4 + reg];
            v += cl[((w * 4 + t) * 64 + llo) * 4 + reg];
        }
        unsafeAtomicAdd(acc + ((size_t)blockIdx.y * SEGS + row) * VALS + cc, v);
    }
}

__global__ __launch_bounds__(256) void vl_finalize(const float* __restrict__ acc,
                                                   float* __restrict__ out)
{
    __shared__ float sum_var[B_];
    __shared__ float num_ids[B_];
    if (threadIdx.x < B_) { sum_var[threadIdx.x] = 0.0f; num_ids[threadIdx.x] = 0.0f; }
    __syncthreads();

    for (int i = threadIdx.x; i < B_ * SEGS; i += 256) {
        const float* a = acc + (size_t)i * VALS;
        const int b = i >> 6;
        const float cnt = a[4];
        if (cnt > 1.0f) {
            const float inv_n = 1.0f / cnt;       // n_safe = cnt (cnt > 0)
            const float denom = cnt - 1.0f;       // cnt > 1
            const float s0 = a[0], s1 = a[1], s2 = a[2];
            const float s3 = cnt - s0 - s1 - s2;  // p's sum to 1 per pixel
            const float ssum2 = s0*s0 + s1*s1 + s2*s2 + s3*s3;
            const float sv = (a[3] - ssum2 * inv_n) / denom;
            atomicAdd(&sum_var[b], sv);
        }
        if (cnt > 0.0f) atomicAdd(&num_ids[b], 1.0f);
    }
    __syncthreads();

    if (threadIdx.x == 0) {
        float loss = 0.0f;
#pragma unroll
        for (int b = 0; b < B_; ++b) loss += sum_var[b] / (num_ids[b] + EPS_);
        out[0] = loss / (float)B_;
    }
}

extern "C" void kernel_launch(void* const* d_in, const int* in_sizes, int n_in,
                              void* d_out, int out_size, void* d_ws, size_t ws_size,
                              hipStream_t stream) {
    const float* logit = (const float*)d_in[0];
    const int*   inst  = (const int*)d_in[1];
    float* out = (float*)d_out;
    float* acc = (float*)d_ws;                      // B_*SEGS*VALS f32 = 10240 B

    const int totalPix = in_sizes[1];               // B*H*W
    const int N = totalPix / B_;                    // H*W per batch

    hipMemsetAsync(acc, 0, (size_t)B_ * SEGS * VALS * sizeof(float), stream);

    const int gridx = 256;                          // 2048 blocks, 8/CU resident
    int ppb = (N + gridx - 1) / gridx;
    ppb = (ppb + 1023) & ~1023;                     // 1024-px block rounds

    dim3 grid(gridx, B_);
    vl_accum<<<grid, 256, 0, stream>>>(logit, inst, acc, N, ppb);
    vl_finalize<<<1, 256, 0, stream>>>(acc, out);
}